// Round 1
// baseline (421.696 us; speedup 1.0000x reference)
//
#include <hip/hip_runtime.h>

// 2-qubit gate application, qubits (5,12) of a 24-qubit fp32 state with
// batch=4 innermost. Element-index bit of qubit t is (23-t)+2 (batch = 2 LSBs):
// qubit 5 -> bit 20, qubit 12 -> bit 13. In float4 units: bits 18 and 11.
// One thread = one float4 (4 batch lanes) x 4 amplitude slots = 64 B in/out.

#define TGT_HI_BIT 18u  // qubit 5, float4 units
#define TGT_LO_BIT 11u  // qubit 12, float4 units

__global__ __launch_bounds__(256) void apply_2q_gate(
    const float4* __restrict__ in,
    const float*  __restrict__ pauli,   // 4x4 row-major: [out_idx][in_idx]
    float4* __restrict__ out)
{
    const unsigned g = blockIdx.x * 256u + threadIdx.x;   // [0, 2^22)

    // Insert zero bits at TGT_LO_BIT and TGT_HI_BIT.
    const unsigned low  =  g               & ((1u << TGT_LO_BIT) - 1u);           // bits 0..10
    const unsigned mid  = (g >> TGT_LO_BIT) & ((1u << (TGT_HI_BIT - TGT_LO_BIT - 1u)) - 1u); // 6 bits
    const unsigned high =  g >> (TGT_HI_BIT - 1u);                                 // remaining
    const unsigned base = low | (mid << (TGT_LO_BIT + 1u)) | (high << (TGT_HI_BIT + 1u));

    const unsigned S0 = 1u << TGT_HI_BIT;  // qubit-5 stride  (j0)
    const unsigned S1 = 1u << TGT_LO_BIT;  // qubit-12 stride (j1)

    // Amplitude order j = j0*2 + j1 (matches pauli column index).
    float4 a[4];
    a[0] = in[base];
    a[1] = in[base + S1];
    a[2] = in[base + S0];
    a[3] = in[base + S0 + S1];

    float p[16];
#pragma unroll
    for (int i = 0; i < 16; ++i) p[i] = pauli[i];

#pragma unroll
    for (int i = 0; i < 4; ++i) {
        float4 r;
        r.x = p[4*i+0]*a[0].x + p[4*i+1]*a[1].x + p[4*i+2]*a[2].x + p[4*i+3]*a[3].x;
        r.y = p[4*i+0]*a[0].y + p[4*i+1]*a[1].y + p[4*i+2]*a[2].y + p[4*i+3]*a[3].y;
        r.z = p[4*i+0]*a[0].z + p[4*i+1]*a[1].z + p[4*i+2]*a[2].z + p[4*i+3]*a[3].z;
        r.w = p[4*i+0]*a[0].w + p[4*i+1]*a[1].w + p[4*i+2]*a[2].w + p[4*i+3]*a[3].w;
        const unsigned off = ((unsigned)i >> 1) * S0 + ((unsigned)i & 1u) * S1;
        out[base + off] = r;
    }
}

extern "C" void kernel_launch(void* const* d_in, const int* in_sizes, int n_in,
                              void* d_out, int out_size, void* d_ws, size_t ws_size,
                              hipStream_t stream) {
    const float4* state = (const float4*)d_in[0];   // 2^26 floats = 2^24 float4
    const float*  pauli = (const float*)d_in[1];    // 16 floats
    float4* out = (float4*)d_out;

    const unsigned n_vec4 = 1u << 22;               // threads: one per float4
    const unsigned block = 256;
    const unsigned grid  = n_vec4 / block;          // 16384 blocks

    apply_2q_gate<<<grid, block, 0, stream>>>(state, pauli, out);
}